// Round 4
// baseline (29.957 us; speedup 1.0000x reference)
//
#include <hip/hip_runtime.h>
#include <math.h>

#define C_ELEC 322.0637f
#define TILE 64
#define CMAX 4

// ---------------------------------------------------------------------------
// Prologue: one record per atom + zero the output accumulators.
//   pos4 = {x, y, z, q}  (q forced 0 for invalid/padded atoms)
//   meta4 = {blk, bt, aw, d2c packed 8b/connection}
// Padded atoms: far-away coords, q=0, blk=B-1 (keeps block ranges monotone).
// ---------------------------------------------------------------------------
__global__ void __launch_bounds__(256)
prologue_kernel(const float* __restrict__ coords,
                const int* __restrict__ offsets,
                const int* __restrict__ block_types,
                const int* __restrict__ bt_n_atoms,
                const float* __restrict__ bt_pc,
                const int* __restrict__ bt_ipd,
                float4* __restrict__ pos4, int4* __restrict__ meta4,
                float* __restrict__ out,
                int P, int A, int Apad, int B, int NBT, int APB, int C)
{
    int idx = blockIdx.x * blockDim.x + threadIdx.x;
    if (idx < P) out[idx] = 0.f;
    int total = P * Apad;
    if (idx >= total) return;
    int p = idx / Apad, a = idx - p * Apad;
    float4 pr; int4 mr;
    if (a >= A) {
        pr = make_float4(1e9f, 1e9f, 1e9f, 0.f);
        mr = make_int4(B - 1, 0, 0, 0);
    } else {
        const float* cp = coords + ((size_t)p * A + a) * 3;
        const int* off = offsets + (size_t)p * B;
        int lo = 0, hi = B;
        while (lo < hi) { int mid = (lo + hi) >> 1; if (off[mid] <= a) lo = mid + 1; else hi = mid; }
        int blk = lo - 1;
        blk = blk < 0 ? 0 : (blk > B - 1 ? B - 1 : blk);
        int aw = a - off[blk];
        int bt = block_types[(size_t)p * B + blk];
        bt = bt < 0 ? 0 : (bt >= NBT ? NBT - 1 : bt);
        int awc = aw < 0 ? 0 : (aw >= APB ? APB - 1 : aw);   // JAX clamps OOB
        float q = bt_pc[(size_t)bt * APB + awc];
        int valid = (aw < bt_n_atoms[bt]) ? 1 : 0;
        int packed = 0;
        int Cc = C > CMAX ? CMAX : C;
        for (int c = 0; c < Cc; ++c)
            packed |= (bt_ipd[((size_t)bt * C + c) * APB + awc] & 0xff) << (8 * c);
        pr = make_float4(cp[0], cp[1], cp[2], valid ? q : 0.f);
        mr = make_int4(blk, bt, awc, packed);
    }
    pos4[idx] = pr;
    meta4[idx] = mr;
}

// ---------------------------------------------------------------------------
// Pair kernel: 64x64 upper-triangular tile pairs. Tables staged in LDS;
// inner loop: cheap d2 mask pass, then per-lane compacted tail over
// survivors only (~4.5% of pairs). Block sum atomically added to out[p].
// ---------------------------------------------------------------------------
__global__ void __launch_bounds__(256)
pair_kernel(const float4* __restrict__ pos4,
            const int4* __restrict__ meta4,
            const int* __restrict__ inter_bondsep,   // P*B*B*C*C
            const int* __restrict__ bt_xpd,          // NBT*APB*APB
            const int* __restrict__ block_types,     // P*B
            const float* __restrict__ gp,
            float* __restrict__ out,
            int P, int Apad, int B, int NBT, int APB, int C, int nt, int TP)
{
    __shared__ float4 s_pos[TILE];
    __shared__ int4 s_meta[TILE];
    __shared__ int4 s_bond[256];      // (bi_rel*nj + bj_rel) -> C*C==4 ints
    __shared__ int s_xpd[2048];       // overlapping blocks' intra tables
    __shared__ float s_red[4];

    int bid = blockIdx.x;
    int p = bid / TP;
    int tp = bid - p * TP;
    int ti = 0, rem = tp;
    while (rem >= nt - ti) { rem -= nt - ti; ++ti; }
    int tj = ti + rem;
    int t = threadIdx.x;
    int ibase = ti * TILE, jbase = tj * TILE;
    bool diag = (ti == tj);

    const float4* ppos = pos4 + (size_t)p * Apad;
    const int4* pmeta = meta4 + (size_t)p * Apad;

    if (t < TILE) {
        s_pos[t] = ppos[ibase + t];
        s_meta[t] = pmeta[ibase + t];
    }
    int jj = t & (TILE - 1);
    int jAtom = jbase + jj;
    float4 pj = ppos[jAtom];
    int4 mj = pmeta[jAtom];
    int blkj = mj.x, awj = mj.z;
    int dj0 = mj.w & 0xff, dj1 = (mj.w >> 8) & 0xff;
    __syncthreads();

    int bi0 = s_meta[0].x, bi1 = s_meta[TILE - 1].x;
    int bj0 = pmeta[jbase].x, bj1 = pmeta[jbase + TILE - 1].x;
    int ni = bi1 - bi0 + 1, nj = bj1 - bj0 + 1;
    int APB2 = APB * APB;

    bool bondC2 = (C == 2) && ni > 0 && nj > 0 && (ni * nj) <= 256;
    int ov0 = bi0 > bj0 ? bi0 : bj0;
    int ov1 = bi1 < bj1 ? bi1 : bj1;
    int nov = ov1 - ov0 + 1;
    bool xpdStaged = nov > 0 && (nov * APB2) <= 2048;

    if (bondC2) {
        int total = ni * nj;
        for (int idx = t; idx < total; idx += 256) {
            int bir = idx / nj, bjr = idx - bir * nj;
            s_bond[idx] = *(const int4*)(inter_bondsep +
                (((size_t)p * B + (bi0 + bir)) * B + (bj0 + bjr)) * 4);
        }
    }
    if (xpdStaged) {
        int total = nov * APB2;
        for (int idx = t; idx < total; idx += 256) {
            int b = idx / APB2, w = idx - b * APB2;
            int bt = block_types[(size_t)p * B + ov0 + b];
            bt = bt < 0 ? 0 : (bt >= NBT ? NBT - 1 : bt);
            s_xpd[idx] = bt_xpd[(size_t)bt * APB2 + w];
        }
    }
    __syncthreads();

    float D = gp[0], D0 = gp[1], S = gp[2], min_dis = gp[3], max_dis = gp[4];
    float max2 = max_dis * max_dis;
    float xm = max_dis * S;
    float esm = D - 0.5f * (D - D0) * (2.f + 2.f * xm + xm * xm) * __expf(-xm);
    float shift = 1.f / (max_dis * esm);
    int Cc = C > CMAX ? CMAX : C;

    float acc = 0.f;
    int lo = (t >> 6) * 16;

    // pass 1: cheap distance/validity mask (8 VALU ops per pair)
    unsigned mask = 0;
    if (pj.w != 0.f) {
        for (int k = 0; k < 16; ++k) {
            int ii = lo + k;
            float4 pi = s_pos[ii];
            float dx = pi.x - pj.x, dy = pi.y - pj.y, dz = pi.z - pj.z;
            float d2 = dx * dx + dy * dy + dz * dz;
            bool ok = (d2 < max2) && (pi.w != 0.f);
            if (diag) ok = ok && (ibase + ii < jAtom);
            mask |= (ok ? 1u : 0u) << k;
        }
    }

    // pass 2: compacted tail — lanes walk their own survivors
    while (mask) {
        int k = __builtin_ctz(mask);
        mask &= mask - 1;
        int ii = lo + k;
        float4 pi = s_pos[ii];
        float dx = pi.x - pj.x, dy = pi.y - pj.y, dz = pi.z - pj.z;
        float d2 = dx * dx + dy * dy + dz * dz;
        int4 mi = s_meta[ii];
        int bi = mi.x;
        int bpl;
        if (bi == blkj) {
            bpl = xpdStaged ? s_xpd[(bi - ov0) * APB2 + mi.z * APB + awj]
                            : bt_xpd[((size_t)mi.y * APB + mi.z) * APB + awj];
        } else if (C == 2) {
            int4 b4 = bondC2 ? s_bond[(bi - bi0) * nj + (blkj - bj0)]
                             : *(const int4*)(inter_bondsep +
                                   (((size_t)p * B + bi) * B + blkj) * 4);
            int di0 = mi.w & 0xff, di1 = (mi.w >> 8) & 0xff;
            bpl = min(min(di0 + b4.x + dj0, di0 + b4.y + dj1),
                      min(di1 + b4.z + dj0, di1 + b4.w + dj1));
        } else {
            const int* ib = inter_bondsep + (((size_t)p * B + bi) * B + blkj) * C * C;
            int best = 0x7fffffff;
            for (int c1 = 0; c1 < Cc; ++c1) {
                int dic = (mi.w >> (8 * c1)) & 0xff;
                for (int c2 = 0; c2 < Cc; ++c2) {
                    int v = dic + ib[c1 * C + c2] + ((mj.w >> (8 * c2)) & 0xff);
                    best = v < best ? v : best;
                }
            }
            bpl = best;
        }
        if (bpl < 4) continue;
        float cpv = bpl > 4 ? 1.f : 0.2f;
        float dist = sqrtf(fmaxf(d2, 1e-12f));
        float dc = fmaxf(dist, min_dis);            // dist < max_dis by mask
        float xs = dc * S;
        float es = D - 0.5f * (D - D0) * (2.f + 2.f * xs + xs * xs) * __expf(-xs);
        acc += C_ELEC * pi.w * pj.w * (1.f / (dc * es) - shift) * cpv;
    }

    for (int off = 32; off; off >>= 1) acc += __shfl_down(acc, off, 64);
    if ((t & 63) == 0) s_red[t >> 6] = acc;
    __syncthreads();
    if (t == 0)
        atomicAdd(&out[p], s_red[0] + s_red[1] + s_red[2] + s_red[3]);
}

extern "C" void kernel_launch(void* const* d_in, const int* in_sizes, int n_in,
                              void* d_out, int out_size, void* d_ws, size_t ws_size,
                              hipStream_t stream) {
    const float* coords        = (const float*)d_in[0];
    const int*   offsets       = (const int*)d_in[1];
    const int*   block_types   = (const int*)d_in[2];
    const int*   inter_bondsep = (const int*)d_in[4];
    const int*   bt_n_atoms    = (const int*)d_in[5];
    const float* bt_pc         = (const float*)d_in[6];
    const int*   bt_ipd        = (const int*)d_in[9];
    const int*   bt_xpd        = (const int*)d_in[10];
    const float* gp            = (const float*)d_in[11];

    int NBT = in_sizes[5];
    int APB = in_sizes[6] / NBT;
    int PB  = in_sizes[1];
    int B   = in_sizes[3] / PB;
    int P   = PB / B;
    int A   = in_sizes[0] / (3 * P);
    int C2  = in_sizes[4] / in_sizes[3];
    int C   = 1;
    while (C * C < C2) ++C;

    int nt = (A + TILE - 1) / TILE;
    int Apad = nt * TILE;
    int TP = nt * (nt + 1) / 2;

    char* ws = (char*)d_ws;
    float4* pos4  = (float4*)ws;
    int4*   meta4 = (int4*)(ws + (size_t)P * Apad * 16);

    int total = P * Apad;
    hipLaunchKernelGGL(prologue_kernel, dim3((total + 255) / 256), dim3(256), 0, stream,
                       coords, offsets, block_types, bt_n_atoms, bt_pc, bt_ipd,
                       pos4, meta4, (float*)d_out, P, A, Apad, B, NBT, APB, C);
    hipLaunchKernelGGL(pair_kernel, dim3(P * TP), dim3(256), 0, stream,
                       pos4, meta4, inter_bondsep, bt_xpd, block_types, gp,
                       (float*)d_out, P, Apad, B, NBT, APB, C, nt, TP);
}

// Round 5
// 19.643 us; speedup vs baseline: 1.5251x; 1.5251x over previous
//
#include <hip/hip_runtime.h>
#include <math.h>

#define C_ELEC 322.0637f
#define TILE 64
#define CMAX 4

// ---------------------------------------------------------------------------
// Prologue: one record per atom.
//   pos4 = {x, y, z, q}  (q forced 0 for invalid/padded atoms)
//   meta4 = {blk, bt, aw, d2c packed 8b/connection}
// Padded atoms: far coords, q=0, blk=B-1 (keeps per-tile block ranges valid).
// ---------------------------------------------------------------------------
__global__ void __launch_bounds__(256)
prologue_kernel(const float* __restrict__ coords,
                const int* __restrict__ offsets,
                const int* __restrict__ block_types,
                const int* __restrict__ bt_n_atoms,
                const float* __restrict__ bt_pc,
                const int* __restrict__ bt_ipd,
                float4* __restrict__ pos4, int4* __restrict__ meta4,
                int P, int A, int Apad, int B, int NBT, int APB, int C)
{
    int idx = blockIdx.x * blockDim.x + threadIdx.x;
    int total = P * Apad;
    if (idx >= total) return;
    int p = idx / Apad, a = idx - p * Apad;
    float4 pr; int4 mr;
    if (a >= A) {
        pr = make_float4(1e9f, 1e9f, 1e9f, 0.f);
        mr = make_int4(B - 1, 0, 0, 0);
    } else {
        const float* cp = coords + ((size_t)p * A + a) * 3;
        const int* off = offsets + (size_t)p * B;
        int lo = 0, hi = B;
        while (lo < hi) { int mid = (lo + hi) >> 1; if (off[mid] <= a) lo = mid + 1; else hi = mid; }
        int blk = lo - 1;
        blk = blk < 0 ? 0 : (blk > B - 1 ? B - 1 : blk);
        int aw = a - off[blk];
        int bt = block_types[(size_t)p * B + blk];
        bt = bt < 0 ? 0 : (bt >= NBT ? NBT - 1 : bt);
        int awc = aw < 0 ? 0 : (aw >= APB ? APB - 1 : aw);   // JAX clamps OOB
        float q = bt_pc[(size_t)bt * APB + awc];
        int valid = (aw < bt_n_atoms[bt]) ? 1 : 0;
        int packed = 0;
        int Cc = C > CMAX ? CMAX : C;
        for (int c = 0; c < Cc; ++c)
            packed |= (bt_ipd[((size_t)bt * C + c) * APB + awc] & 0xff) << (8 * c);
        pr = make_float4(cp[0], cp[1], cp[2], valid ? q : 0.f);
        mr = make_int4(blk, bt, awc, packed);
    }
    pos4[idx] = pr;
    meta4[idx] = mr;
}

// ---------------------------------------------------------------------------
// Pair kernel: 64x64 upper-triangular tile pairs.
//   pass 1: cheap d2/validity filter (broadcast LDS reads), survivors appended
//           to an LDS queue (LDS atomic; worst case 4096 entries = no overflow)
//   pass 2: all 256 threads process the ~4.5% survivors at full occupancy.
// Tables (inter_bondsep block-pairs, intra xpd) staged in LDS.
// ---------------------------------------------------------------------------
__global__ void __launch_bounds__(256)
pair_kernel(const float4* __restrict__ pos4,
            const int4* __restrict__ meta4,
            const int* __restrict__ inter_bondsep,   // P*B*B*C*C
            const int* __restrict__ bt_xpd,          // NBT*APB*APB
            const int* __restrict__ block_types,     // P*B
            const float* __restrict__ gp,
            float* __restrict__ partials,
            int P, int Apad, int B, int NBT, int APB, int C, int nt, int TP)
{
    __shared__ float4 s_posi[TILE], s_posj[TILE];
    __shared__ int4 s_meti[TILE], s_metj[TILE];
    __shared__ int4 s_bond[256];          // (bi_rel*nj + bj_rel) -> C*C==4 ints
    __shared__ int s_xpd[2048];           // overlapping blocks' intra tables
    __shared__ unsigned short s_list[TILE * TILE];   // survivor queue (worst case)
    __shared__ int s_cnt;
    __shared__ float s_red[4];

    int bid = blockIdx.x;
    int p = bid / TP;
    int tp = bid - p * TP;
    int ti = 0, rem = tp;
    while (rem >= nt - ti) { rem -= nt - ti; ++ti; }
    int tj = ti + rem;
    int t = threadIdx.x;
    int ibase = ti * TILE, jbase = tj * TILE;
    bool diag = (ti == tj);

    const float4* ppos = pos4 + (size_t)p * Apad;
    const int4* pmeta = meta4 + (size_t)p * Apad;

    if (t < TILE) {
        s_posi[t] = ppos[ibase + t];
        s_meti[t] = pmeta[ibase + t];
    } else if (t < 2 * TILE) {
        s_posj[t - TILE] = ppos[jbase + t - TILE];
        s_metj[t - TILE] = pmeta[jbase + t - TILE];
    }
    if (t == 0) s_cnt = 0;
    __syncthreads();

    // block ranges (blk monotone in atom index)
    int bi0 = s_meti[0].x, bi1 = s_meti[TILE - 1].x;
    int bj0 = s_metj[0].x, bj1 = s_metj[TILE - 1].x;
    int ni = bi1 - bi0 + 1, nj = bj1 - bj0 + 1;
    int APB2 = APB * APB;

    bool bondC2 = (C == 2) && (ni * nj) <= 256;
    int ov0 = bi0 > bj0 ? bi0 : bj0;
    int ov1 = bi1 < bj1 ? bi1 : bj1;
    int nov = ov1 - ov0 + 1;
    bool xpdStaged = nov > 0 && (nov * APB2) <= 2048;

    if (bondC2) {
        int total = ni * nj;
        for (int idx = t; idx < total; idx += 256) {
            int bir = idx / nj, bjr = idx - bir * nj;
            s_bond[idx] = *(const int4*)(inter_bondsep +
                (((size_t)p * B + (bi0 + bir)) * B + (bj0 + bjr)) * 4);
        }
    }
    if (xpdStaged) {
        int total = nov * APB2;
        for (int idx = t; idx < total; idx += 256) {
            int b = idx / APB2, w = idx - b * APB2;
            int bt = block_types[(size_t)p * B + ov0 + b];
            bt = bt < 0 ? 0 : (bt >= NBT ? NBT - 1 : bt);
            s_xpd[idx] = bt_xpd[(size_t)bt * APB2 + w];
        }
    }
    __syncthreads();

    float D = gp[0], D0 = gp[1], S = gp[2], min_dis = gp[3], max_dis = gp[4];
    float max2 = max_dis * max_dis;
    float xm = max_dis * S;
    float esm = D - 0.5f * (D - D0) * (2.f + 2.f * xm + xm * xm) * __expf(-xm);
    float shift = 1.f / (max_dis * esm);
    int Cc = C > CMAX ? CMAX : C;

    // ---- pass 1: filter, append survivors ----
    int jj = t & (TILE - 1);
    int lo = (t >> 6) * 16;
    float4 pj = s_posj[jj];
    if (pj.w != 0.f) {
        for (int k = 0; k < 16; ++k) {
            int ii = lo + k;
            float4 pi = s_posi[ii];                 // broadcast, conflict-free
            float dx = pi.x - pj.x, dy = pi.y - pj.y, dz = pi.z - pj.z;
            float d2 = dx * dx + dy * dy + dz * dz;
            bool ok = (d2 < max2) && (pi.w != 0.f);
            if (diag) ok = ok && (ii < jj);
            if (ok) {
                int slot = atomicAdd(&s_cnt, 1);
                s_list[slot] = (unsigned short)(ii | (jj << 6));
            }
        }
    }
    __syncthreads();
    int cnt = s_cnt;

    // ---- pass 2: process survivors at full lane occupancy ----
    float acc = 0.f;
    for (int e = t; e < cnt; e += 256) {
        int ent = s_list[e];
        int ii = ent & 63, j2 = ent >> 6;
        float4 pi = s_posi[ii];
        float4 pjv = s_posj[j2];
        float dx = pi.x - pjv.x, dy = pi.y - pjv.y, dz = pi.z - pjv.z;
        float d2 = dx * dx + dy * dy + dz * dz;
        int4 mi = s_meti[ii];
        int4 mjv = s_metj[j2];
        int bi = mi.x, bj = mjv.x;
        int bpl;
        if (bi == bj) {
            bpl = xpdStaged ? s_xpd[(bi - ov0) * APB2 + mi.z * APB + mjv.z]
                            : bt_xpd[((size_t)mi.y * APB + mi.z) * APB + mjv.z];
        } else if (C == 2) {
            int4 b4 = bondC2 ? s_bond[(bi - bi0) * nj + (bj - bj0)]
                             : *(const int4*)(inter_bondsep +
                                   (((size_t)p * B + bi) * B + bj) * 4);
            int di0 = mi.w & 0xff, di1 = (mi.w >> 8) & 0xff;
            int dj0 = mjv.w & 0xff, dj1 = (mjv.w >> 8) & 0xff;
            bpl = min(min(di0 + b4.x + dj0, di0 + b4.y + dj1),
                      min(di1 + b4.z + dj0, di1 + b4.w + dj1));
        } else {
            const int* ib = inter_bondsep + (((size_t)p * B + bi) * B + bj) * C * C;
            int best = 0x7fffffff;
            for (int c1 = 0; c1 < Cc; ++c1) {
                int dic = (mi.w >> (8 * c1)) & 0xff;
                for (int c2 = 0; c2 < Cc; ++c2) {
                    int v = dic + ib[c1 * C + c2] + ((mjv.w >> (8 * c2)) & 0xff);
                    best = v < best ? v : best;
                }
            }
            bpl = best;
        }
        if (bpl < 4) continue;
        float cpv = bpl > 4 ? 1.f : 0.2f;
        float dist = sqrtf(fmaxf(d2, 1e-12f));
        float dc = fmaxf(dist, min_dis);            // dist < max_dis by pass 1
        float xs = dc * S;
        float es = D - 0.5f * (D - D0) * (2.f + 2.f * xs + xs * xs) * __expf(-xs);
        acc += C_ELEC * pi.w * pjv.w * (1.f / (dc * es) - shift) * cpv;
    }

    for (int off = 32; off; off >>= 1) acc += __shfl_down(acc, off, 64);
    if ((t & 63) == 0) s_red[t >> 6] = acc;
    __syncthreads();
    if (t == 0) partials[bid] = s_red[0] + s_red[1] + s_red[2] + s_red[3];
}

__global__ void __launch_bounds__(256)
reduce_kernel(const float* __restrict__ partials, float* __restrict__ out, int TP)
{
    int p = blockIdx.x;
    float acc = 0.f;
    for (int i = threadIdx.x; i < TP; i += 256) acc += partials[(size_t)p * TP + i];
    for (int off = 32; off; off >>= 1) acc += __shfl_down(acc, off, 64);
    __shared__ float s[4];
    if ((threadIdx.x & 63) == 0) s[threadIdx.x >> 6] = acc;
    __syncthreads();
    if (threadIdx.x == 0) out[p] = s[0] + s[1] + s[2] + s[3];
}

extern "C" void kernel_launch(void* const* d_in, const int* in_sizes, int n_in,
                              void* d_out, int out_size, void* d_ws, size_t ws_size,
                              hipStream_t stream) {
    const float* coords        = (const float*)d_in[0];
    const int*   offsets       = (const int*)d_in[1];
    const int*   block_types   = (const int*)d_in[2];
    const int*   inter_bondsep = (const int*)d_in[4];
    const int*   bt_n_atoms    = (const int*)d_in[5];
    const float* bt_pc         = (const float*)d_in[6];
    const int*   bt_ipd        = (const int*)d_in[9];
    const int*   bt_xpd        = (const int*)d_in[10];
    const float* gp            = (const float*)d_in[11];

    int NBT = in_sizes[5];
    int APB = in_sizes[6] / NBT;
    int PB  = in_sizes[1];
    int B   = in_sizes[3] / PB;
    int P   = PB / B;
    int A   = in_sizes[0] / (3 * P);
    int C2  = in_sizes[4] / in_sizes[3];
    int C   = 1;
    while (C * C < C2) ++C;

    int nt = (A + TILE - 1) / TILE;
    int Apad = nt * TILE;
    int TP = nt * (nt + 1) / 2;

    char* ws = (char*)d_ws;
    float4* pos4    = (float4*)ws;
    int4*   meta4   = (int4*)(ws + (size_t)P * Apad * 16);
    float*  partials = (float*)(ws + (size_t)P * Apad * 32);

    int total = P * Apad;
    hipLaunchKernelGGL(prologue_kernel, dim3((total + 255) / 256), dim3(256), 0, stream,
                       coords, offsets, block_types, bt_n_atoms, bt_pc, bt_ipd,
                       pos4, meta4, P, A, Apad, B, NBT, APB, C);
    hipLaunchKernelGGL(pair_kernel, dim3(P * TP), dim3(256), 0, stream,
                       pos4, meta4, inter_bondsep, bt_xpd, block_types, gp,
                       partials, P, Apad, B, NBT, APB, C, nt, TP);
    hipLaunchKernelGGL(reduce_kernel, dim3(P), dim3(256), 0, stream,
                       partials, (float*)d_out, TP);
}

// Round 6
// 16.241 us; speedup vs baseline: 1.8446x; 1.2095x over previous
//
#include <hip/hip_runtime.h>
#include <math.h>

#define C_ELEC 322.0637f
#define TILE 64
#define CMAX 4
#define BMAX 256   // max per-pose block count staged in LDS (global fallback past this)

// ---------------------------------------------------------------------------
// Fused pair kernel: 64x64 upper-triangular tile pairs, one block each.
//   phase 0: stage offsets/block_types (LDS), compute this block's 128 atom
//            records in-block (binary search over LDS offsets).
//   phase 1: stage bond-path tables (inter-block int4s, overlapping intra).
//   phase 2: cheap d2/validity filter -> LDS survivor queue.
//   phase 3: all 256 threads process ~4.5% survivors at full occupancy.
// Block partial -> partials[bid]; separate tiny reduce kernel (no device-
// scope sync at block end: rounds 2/4 showed that costs ~5 us).
// ---------------------------------------------------------------------------
__global__ void __launch_bounds__(256)
pair_kernel(const float* __restrict__ coords,
            const int* __restrict__ offsets,         // P*B
            const int* __restrict__ block_types,     // P*B
            const int* __restrict__ inter_bondsep,   // P*B*B*C*C
            const int* __restrict__ bt_n_atoms,      // NBT
            const float* __restrict__ bt_pc,         // NBT*APB
            const int* __restrict__ bt_ipd,          // NBT*C*APB
            const int* __restrict__ bt_xpd,          // NBT*APB*APB
            const float* __restrict__ gp,
            float* __restrict__ partials,
            int P, int A, int B, int NBT, int APB, int C, int nt, int TP)
{
    __shared__ float4 s_posi[TILE], s_posj[TILE];
    __shared__ int4 s_meti[TILE], s_metj[TILE];
    __shared__ int4 s_bond[256];          // (bi_rel*nj + bj_rel) -> C*C==4 ints
    __shared__ int s_xpd[2048];           // overlapping blocks' intra tables
    __shared__ unsigned short s_list[TILE * TILE];   // survivor queue
    __shared__ int s_off[BMAX];
    __shared__ int s_btype[BMAX];
    __shared__ int s_cnt;
    __shared__ float s_red[4];

    int bid = blockIdx.x;
    int p = bid / TP;
    int tp = bid - p * TP;
    int ti = 0, rem = tp;
    while (rem >= nt - ti) { rem -= nt - ti; ++ti; }
    int tj = ti + rem;
    int t = threadIdx.x;
    int ibase = ti * TILE, jbase = tj * TILE;
    bool diag = (ti == tj);
    bool bLds = (B <= BMAX);

    // ---- phase 0a: stage per-pose offsets / block types ----
    int nb = bLds ? B : BMAX;
    for (int i = t; i < nb; i += 256) {
        s_off[i] = offsets[(size_t)p * B + i];
        s_btype[i] = block_types[(size_t)p * B + i];
    }
    if (t == 0) s_cnt = 0;
    __syncthreads();

    // ---- phase 0b: compute this block's atom records in-block ----
    if (t < 2 * TILE) {
        int local = t < TILE ? t : t - TILE;
        int a = (t < TILE) ? ibase + local : jbase + local;
        float4 pr; int4 mr;
        if (a >= A) {
            pr = make_float4(1e9f, 1e9f, 1e9f, 0.f);
            mr = make_int4(B - 1, 0, 0, 0);
        } else {
            const float* cp = coords + ((size_t)p * A + a) * 3;
            float x = cp[0], y = cp[1], z = cp[2];
            int lo = 0, hi = B;
            if (bLds) {
                while (lo < hi) { int mid = (lo + hi) >> 1; if (s_off[mid] <= a) lo = mid + 1; else hi = mid; }
            } else {
                const int* off = offsets + (size_t)p * B;
                while (lo < hi) { int mid = (lo + hi) >> 1; if (off[mid] <= a) lo = mid + 1; else hi = mid; }
            }
            int blk = lo - 1;
            blk = blk < 0 ? 0 : (blk > B - 1 ? B - 1 : blk);
            int aw = a - (bLds ? s_off[blk] : offsets[(size_t)p * B + blk]);
            int bt = bLds ? s_btype[blk] : block_types[(size_t)p * B + blk];
            bt = bt < 0 ? 0 : (bt >= NBT ? NBT - 1 : bt);
            int awc = aw < 0 ? 0 : (aw >= APB ? APB - 1 : aw);   // JAX clamps OOB
            float q = bt_pc[(size_t)bt * APB + awc];
            int valid = (aw < bt_n_atoms[bt]) ? 1 : 0;
            int packed = 0;
            int Cc = C > CMAX ? CMAX : C;
            for (int c = 0; c < Cc; ++c)
                packed |= (bt_ipd[((size_t)bt * C + c) * APB + awc] & 0xff) << (8 * c);
            pr = make_float4(x, y, z, valid ? q : 0.f);
            mr = make_int4(blk, bt, awc, packed);
        }
        if (t < TILE) { s_posi[local] = pr; s_meti[local] = mr; }
        else          { s_posj[local] = pr; s_metj[local] = mr; }
    }
    __syncthreads();

    // ---- phase 1: stage bond-path tables ----
    int bi0 = s_meti[0].x, bi1 = s_meti[TILE - 1].x;
    int bj0 = s_metj[0].x, bj1 = s_metj[TILE - 1].x;
    int ni = bi1 - bi0 + 1, nj = bj1 - bj0 + 1;
    int APB2 = APB * APB;

    bool bondC2 = (C == 2) && (ni * nj) <= 256;
    int ov0 = bi0 > bj0 ? bi0 : bj0;
    int ov1 = bi1 < bj1 ? bi1 : bj1;
    int nov = ov1 - ov0 + 1;
    bool xpdStaged = nov > 0 && (nov * APB2) <= 2048;

    if (bondC2) {
        int total = ni * nj;
        for (int idx = t; idx < total; idx += 256) {
            int bir = idx / nj, bjr = idx - bir * nj;
            s_bond[idx] = *(const int4*)(inter_bondsep +
                (((size_t)p * B + (bi0 + bir)) * B + (bj0 + bjr)) * 4);
        }
    }
    if (xpdStaged) {
        int total = nov * APB2;
        for (int idx = t; idx < total; idx += 256) {
            int b = idx / APB2, w = idx - b * APB2;
            int bt = bLds ? s_btype[ov0 + b] : block_types[(size_t)p * B + ov0 + b];
            bt = bt < 0 ? 0 : (bt >= NBT ? NBT - 1 : bt);
            s_xpd[idx] = bt_xpd[(size_t)bt * APB2 + w];
        }
    }
    __syncthreads();

    float D = gp[0], D0 = gp[1], S = gp[2], min_dis = gp[3], max_dis = gp[4];
    float max2 = max_dis * max_dis;
    float xm = max_dis * S;
    float esm = D - 0.5f * (D - D0) * (2.f + 2.f * xm + xm * xm) * __expf(-xm);
    float shift = 1.f / (max_dis * esm);
    int Cc = C > CMAX ? CMAX : C;

    // ---- phase 2: filter, append survivors ----
    int jj = t & (TILE - 1);
    int lo16 = (t >> 6) * 16;
    float4 pj = s_posj[jj];
    if (pj.w != 0.f) {
        for (int k = 0; k < 16; ++k) {
            int ii = lo16 + k;
            float4 pi = s_posi[ii];                 // broadcast, conflict-free
            float dx = pi.x - pj.x, dy = pi.y - pj.y, dz = pi.z - pj.z;
            float d2 = dx * dx + dy * dy + dz * dz;
            bool ok = (d2 < max2) && (pi.w != 0.f);
            if (diag) ok = ok && (ii < jj);
            if (ok) {
                int slot = atomicAdd(&s_cnt, 1);
                s_list[slot] = (unsigned short)(ii | (jj << 6));
            }
        }
    }
    __syncthreads();
    int cnt = s_cnt;

    // ---- phase 3: process survivors at full lane occupancy ----
    float acc = 0.f;
    for (int e = t; e < cnt; e += 256) {
        int ent = s_list[e];
        int ii = ent & 63, j2 = ent >> 6;
        float4 pi = s_posi[ii];
        float4 pjv = s_posj[j2];
        float dx = pi.x - pjv.x, dy = pi.y - pjv.y, dz = pi.z - pjv.z;
        float d2 = dx * dx + dy * dy + dz * dz;
        int4 mi = s_meti[ii];
        int4 mjv = s_metj[j2];
        int bi = mi.x, bj = mjv.x;
        int bpl;
        if (bi == bj) {
            bpl = xpdStaged ? s_xpd[(bi - ov0) * APB2 + mi.z * APB + mjv.z]
                            : bt_xpd[((size_t)mi.y * APB + mi.z) * APB + mjv.z];
        } else if (C == 2) {
            int4 b4 = bondC2 ? s_bond[(bi - bi0) * nj + (bj - bj0)]
                             : *(const int4*)(inter_bondsep +
                                   (((size_t)p * B + bi) * B + bj) * 4);
            int di0 = mi.w & 0xff, di1 = (mi.w >> 8) & 0xff;
            int dj0 = mjv.w & 0xff, dj1 = (mjv.w >> 8) & 0xff;
            bpl = min(min(di0 + b4.x + dj0, di0 + b4.y + dj1),
                      min(di1 + b4.z + dj0, di1 + b4.w + dj1));
        } else {
            const int* ib = inter_bondsep + (((size_t)p * B + bi) * B + bj) * C * C;
            int best = 0x7fffffff;
            for (int c1 = 0; c1 < Cc; ++c1) {
                int dic = (mi.w >> (8 * c1)) & 0xff;
                for (int c2 = 0; c2 < Cc; ++c2) {
                    int v = dic + ib[c1 * C + c2] + ((mjv.w >> (8 * c2)) & 0xff);
                    best = v < best ? v : best;
                }
            }
            bpl = best;
        }
        if (bpl < 4) continue;
        float cpv = bpl > 4 ? 1.f : 0.2f;
        float dist = sqrtf(fmaxf(d2, 1e-12f));
        float dc = fmaxf(dist, min_dis);            // dist < max_dis by phase 2
        float xs = dc * S;
        float es = D - 0.5f * (D - D0) * (2.f + 2.f * xs + xs * xs) * __expf(-xs);
        acc += C_ELEC * pi.w * pjv.w * (1.f / (dc * es) - shift) * cpv;
    }

    for (int off = 32; off; off >>= 1) acc += __shfl_down(acc, off, 64);
    if ((t & 63) == 0) s_red[t >> 6] = acc;
    __syncthreads();
    if (t == 0) partials[bid] = s_red[0] + s_red[1] + s_red[2] + s_red[3];
}

__global__ void __launch_bounds__(256)
reduce_kernel(const float* __restrict__ partials, float* __restrict__ out, int TP)
{
    int p = blockIdx.x;
    float acc = 0.f;
    for (int i = threadIdx.x; i < TP; i += 256) acc += partials[(size_t)p * TP + i];
    for (int off = 32; off; off >>= 1) acc += __shfl_down(acc, off, 64);
    __shared__ float s[4];
    if ((threadIdx.x & 63) == 0) s[threadIdx.x >> 6] = acc;
    __syncthreads();
    if (threadIdx.x == 0) out[p] = s[0] + s[1] + s[2] + s[3];
}

extern "C" void kernel_launch(void* const* d_in, const int* in_sizes, int n_in,
                              void* d_out, int out_size, void* d_ws, size_t ws_size,
                              hipStream_t stream) {
    const float* coords        = (const float*)d_in[0];
    const int*   offsets       = (const int*)d_in[1];
    const int*   block_types   = (const int*)d_in[2];
    const int*   inter_bondsep = (const int*)d_in[4];
    const int*   bt_n_atoms    = (const int*)d_in[5];
    const float* bt_pc         = (const float*)d_in[6];
    const int*   bt_ipd        = (const int*)d_in[9];
    const int*   bt_xpd        = (const int*)d_in[10];
    const float* gp            = (const float*)d_in[11];

    int NBT = in_sizes[5];
    int APB = in_sizes[6] / NBT;
    int PB  = in_sizes[1];
    int B   = in_sizes[3] / PB;
    int P   = PB / B;
    int A   = in_sizes[0] / (3 * P);
    int C2  = in_sizes[4] / in_sizes[3];
    int C   = 1;
    while (C * C < C2) ++C;

    int nt = (A + TILE - 1) / TILE;
    int TP = nt * (nt + 1) / 2;

    float* partials = (float*)d_ws;   // P*TP floats, fully overwritten each call

    hipLaunchKernelGGL(pair_kernel, dim3(P * TP), dim3(256), 0, stream,
                       coords, offsets, block_types, inter_bondsep, bt_n_atoms,
                       bt_pc, bt_ipd, bt_xpd, gp, partials,
                       P, A, B, NBT, APB, C, nt, TP);
    hipLaunchKernelGGL(reduce_kernel, dim3(P), dim3(256), 0, stream,
                       partials, (float*)d_out, TP);
}